// Round 1
// 80.095 us; speedup vs baseline: 1.0032x; 1.0032x over previous
//
#include <hip/hip_runtime.h>

// out[b][j] = table_bits[idx(b)][j]; idx(b) = MSB-first pack of (idx_bits[b][k] > 0).
// R8 = single-barrier restructure of R7 (80.35 us). Ledger: R1 80.7 / R2 80.2 /
// R4(NT) 87.5 / R5(2-kernel) 91.3 / R6(ballot) 84.1 / R7(gload_lds) 80.35.
// Changes vs R7:
//   * ROWS 256->512, THREADS 256->512, grid 1024->512: table staged half as
//     often (16 MB -> 8 MB fetch), prologue amortized 2x.
//   * idx path fully de-LDS'd: each thread packs its OWN row's 6-bit index
//     from global (3x int2, 24 B contiguous per lane), then the store loop
//     broadcasts it wave-internally via __shfl (ds_bpermute, hoisted 16x
//     upfront). Removes s_raw (6 KB), s_idx (1 KB), the pack phase, and one
//     of the two __syncthreads.
//   * Hot loop chain shortens from ds_read_b32 -> ds_read_b128 -> store to
//     ds_read_b128 -> store.
// Window floor ~= 57 us harness re-poison + ~11.5 us kernel streaming minimum.

#define THREADS 512
#define ROWS    512            // one row per thread

typedef float nfloat4 __attribute__((ext_vector_type(4)));
typedef int   nint2   __attribute__((ext_vector_type(2)));
#define GLOBAL_AS __attribute__((address_space(1)))
#define LDS_AS    __attribute__((address_space(3)))

__global__ __launch_bounds__(THREADS) void
spike_lut_kernel(const float* __restrict__ table,      // [64 rows][64 bits] float32
                 const int* __restrict__ idx_bits,     // [batch][6] int32
                 nfloat4* __restrict__ out4,           // [batch][16] float4
                 int batch) {
    __shared__ nfloat4 s_table[64 * 16];   // 16 KB full table, linear

    const int  tid = threadIdx.x;
    const int  wv  = tid >> 6;             // wave id (0..7)
    const int  ln  = tid & 63;             // lane id
    const long b0  = (long)blockIdx.x * ROWS;

    const nfloat4* t4 = (const nfloat4*)table;

    // --- Stage table via async global->LDS: LDS dest = wave-uniform base +
    // lane*16. 8 waves x 2 slices x (64 lanes x 16 B) = 16 KB. Table rows are
    // always all valid, so no guard needed even in tail blocks.
    #pragma unroll
    for (int r = 0; r < 2; ++r) {
        const int e = r * 512 + wv * 64;   // float4-element base, wave-uniform
        __builtin_amdgcn_global_load_lds(
            (const GLOBAL_AS void*)(t4 + e + ln),
            (LDS_AS void*)&s_table[e], 16, 0, 0);
    }

    // --- Each thread packs its own row's 6-bit index straight from global.
    // Byte offset row*24 is 8 B aligned -> 3x int2 loads, 24 B/lane contiguous
    // (1.5 KB per wave). k=0 is the MSB (weight 32).
    const long row  = b0 + tid;
    int        myidx = 0;
    if (row < batch) {
        const nint2* p = (const nint2*)(idx_bits + row * 6);
        const nint2 a = p[0], b = p[1], c = p[2];
        myidx = ((a.x > 0) << 5) | ((a.y > 0) << 4) |
                ((b.x > 0) << 3) | ((b.y > 0) << 2) |
                ((c.x > 0) << 1) |  (c.y > 0);
    }

    __syncthreads();   // drains vmcnt (incl. global_load_lds) before LDS reads

    // --- Store loop: wave wv owns rows [wv*64, wv*64+64). Iteration it emits
    // rows wv*64 + it*4 + {0..3}, 16 lanes per row (q = ln&15) -> each wave
    // stores 1 KB contiguous global_store_dwordx4 per iteration. The owning
    // lane of row wv*64+s is lane s of the same wave -> __shfl broadcast, no
    // LDS, no second barrier. Gather ds_read_b128 is conflict-free (16 lanes
    // sweep one 256 B row = all 32 banks).
    const int q = ln & 15;
    if (b0 + ROWS <= batch) {              // uniform per block; exact at 262144
        #pragma unroll
        for (int it = 0; it < 16; ++it) {
            const int  s    = it * 4 + (ln >> 4);          // row-in-slice 0..63
            const int  ridx = __shfl(myidx, s, 64);
            const long r    = b0 + wv * 64 + s;
            out4[r * 16 + q] = s_table[ridx * 16 + q];
        }
    } else {
        #pragma unroll
        for (int it = 0; it < 16; ++it) {
            const int  s    = it * 4 + (ln >> 4);
            const int  ridx = __shfl(myidx, s, 64);
            const long r    = b0 + wv * 64 + s;
            if (r < batch)
                out4[r * 16 + q] = s_table[ridx * 16 + q];
        }
    }
}

extern "C" void kernel_launch(void* const* d_in, const int* in_sizes, int n_in,
                              void* d_out, int out_size, void* d_ws, size_t ws_size,
                              hipStream_t stream) {
    const float* table    = (const float*)d_in[0];   // [64,64] float32
    const int*   idx_bits = (const int*)d_in[1];     // [batch,6] int32
    nfloat4*     out4     = (nfloat4*)d_out;

    const int batch  = in_sizes[1] / 6;
    const int blocks = (batch + ROWS - 1) / ROWS;

    spike_lut_kernel<<<blocks, THREADS, 0, stream>>>(table, idx_bits, out4, batch);
}

// Round 2
// 80.043 us; speedup vs baseline: 1.0039x; 1.0007x over previous
//
#include <hip/hip_runtime.h>

// out[b][j] = table_bits[idx(b)][j]; idx(b) = MSB-first pack of (idx_bits[b][k] > 0).
// R9 = occupancy-doubled R8. Ledger: R1 80.7 / R2 80.2 / R4(NT) 87.5 /
// R5(2-kernel) 91.3 / R6(ballot) 84.1 / R7(gload_lds) 80.35 / R8(1-barrier) 80.10.
// R8's null (removed barrier+pack+8MB fetch = +-0) says the kernel is bound by
// the WRITE STREAM. Last untested lever: waves in flight. One-row-per-thread
// caps the chip at 4096 waves = 16 waves/CU (half capacity). This version
// halves rows-per-wave (32 rows, 8 store iters): 256 thr / 128 rows / 2048
// blocks -> 8 blocks/CU x 4 waves = 32 waves/CU (LDS 128 KB/CU <= 160), 2x the
// outstanding stores. Lanes 32-63 duplicate lanes 0-31's idx pack -- same
// cachelines within the wave, zero extra HBM traffic. Store stays 1 KB
// contiguous per wave-instruction.
// If this is neutral: write stream is BW-saturated -> roofline.

#define THREADS 256
#define ROWS    128            // 4 waves x 32 rows

typedef float nfloat4 __attribute__((ext_vector_type(4)));
typedef int   nint2   __attribute__((ext_vector_type(2)));
#define GLOBAL_AS __attribute__((address_space(1)))
#define LDS_AS    __attribute__((address_space(3)))

__global__ __launch_bounds__(THREADS) void
spike_lut_kernel(const float* __restrict__ table,      // [64 rows][64 bits] float32
                 const int* __restrict__ idx_bits,     // [batch][6] int32
                 nfloat4* __restrict__ out4,           // [batch][16] float4
                 int batch) {
    __shared__ nfloat4 s_table[64 * 16];   // 16 KB full table, linear

    const int  tid = threadIdx.x;
    const int  wv  = tid >> 6;             // wave id (0..3)
    const int  ln  = tid & 63;             // lane id
    const long b0  = (long)blockIdx.x * ROWS;

    const nfloat4* t4 = (const nfloat4*)table;

    // --- Stage table via async global->LDS: LDS dest = wave-uniform base +
    // lane*16. 4 waves x 4 slices x (64 lanes x 16 B) = 16 KB.
    #pragma unroll
    for (int r = 0; r < 4; ++r) {
        const int e = r * 256 + wv * 64;   // float4-element base, wave-uniform
        __builtin_amdgcn_global_load_lds(
            (const GLOBAL_AS void*)(t4 + e + ln),
            (LDS_AS void*)&s_table[e], 16, 0, 0);
    }

    // --- Each lane packs the 6-bit index of row (wv*32 + (ln&31)). Lanes
    // 32-63 duplicate lanes 0-31 (same addresses in-wave -> coalesced, free).
    // 3x int2 = 24 B contiguous per row. k=0 is the MSB (weight 32).
    const int  myrow = wv * 32 + (ln & 31);
    const long row   = b0 + myrow;
    int        myidx = 0;
    if (row < batch) {
        const nint2* p = (const nint2*)(idx_bits + row * 6);
        const nint2 a = p[0], b = p[1], c = p[2];
        myidx = ((a.x > 0) << 5) | ((a.y > 0) << 4) |
                ((b.x > 0) << 3) | ((b.y > 0) << 2) |
                ((c.x > 0) << 1) |  (c.y > 0);
    }

    __syncthreads();   // drains vmcnt (incl. global_load_lds) before LDS reads

    // --- Store loop: wave wv owns rows [wv*32, wv*32+32). Iteration it emits
    // rows wv*32 + it*4 + {0..3}, 16 lanes per row (q = ln&15) -> 1 KB
    // contiguous global_store_dwordx4 per wave-instruction. Owning lane of
    // slice-row s is lane s (s <= 31) -> __shfl broadcast, no LDS for idx.
    // Gather ds_read_b128 is conflict-free (16 lanes sweep one 256 B row).
    const int q = ln & 15;
    if (b0 + ROWS <= batch) {              // uniform per block; exact at 262144
        #pragma unroll
        for (int it = 0; it < 8; ++it) {
            const int  s    = it * 4 + (ln >> 4);          // row-in-slice 0..31
            const int  ridx = __shfl(myidx, s, 64);
            const long r    = b0 + wv * 32 + s;
            out4[r * 16 + q] = s_table[ridx * 16 + q];
        }
    } else {
        #pragma unroll
        for (int it = 0; it < 8; ++it) {
            const int  s    = it * 4 + (ln >> 4);
            const int  ridx = __shfl(myidx, s, 64);
            const long r    = b0 + wv * 32 + s;
            if (r < batch)
                out4[r * 16 + q] = s_table[ridx * 16 + q];
        }
    }
}

extern "C" void kernel_launch(void* const* d_in, const int* in_sizes, int n_in,
                              void* d_out, int out_size, void* d_ws, size_t ws_size,
                              hipStream_t stream) {
    const float* table    = (const float*)d_in[0];   // [64,64] float32
    const int*   idx_bits = (const int*)d_in[1];     // [batch,6] int32
    nfloat4*     out4     = (nfloat4*)d_out;

    const int batch  = in_sizes[1] / 6;
    const int blocks = (batch + ROWS - 1) / ROWS;

    spike_lut_kernel<<<blocks, THREADS, 0, stream>>>(table, idx_bits, out4, batch);
}